// Round 1
// baseline (2179.278 us; speedup 1.0000x reference)
//
#include <hip/hip_runtime.h>
#include <hip/hip_bf16.h>

// GraphFilter: out = sum_k (S^k x) @ W_k,  S = symmetric scatter-add adjacency
// N=100000, E=3200000, FIN=FOUT=256, K=4.
// Strategy: device CSR build -> 3x gather SpMM (bf16 storage, fp32 accum, one
// wave per node) -> single fused MFMA GEMM [N,1024]@[1024,256] bf16->fp32.

#define NNODES 100000
#define NEDGES 3200000
#define FINF   256
#define FOUTF  256
#define KTOT   1024            // K * FIN
#define MPAD   100096          // 782 * 128 (M padded to 128-row tiles)
#define MTILES 782
#define SB     98              // scan blocks: ceil(N/1024)

typedef __attribute__((ext_vector_type(8))) short bf16x8;
typedef __attribute__((ext_vector_type(4))) float f32x4;

__device__ __forceinline__ float bf2f(unsigned short u) {
  return __uint_as_float(((unsigned int)u) << 16);
}
__device__ __forceinline__ unsigned short f2bf(float f) {
  unsigned int u = __float_as_uint(f);
  unsigned int r = (u + 0x7fffu + ((u >> 16) & 1u)) >> 16;
  return (unsigned short)r;
}

__device__ __forceinline__ void async_ld16(const void* g, void* l) {
  __builtin_amdgcn_global_load_lds(
      (const __attribute__((address_space(1))) unsigned int*)g,
      (__attribute__((address_space(3))) unsigned int*)l, 16, 0, 0);
}

// ---------------- CSR build ----------------

__global__ void count_deg_kernel(const int* __restrict__ ei, int* __restrict__ deg) {
  for (int e = blockIdx.x * blockDim.x + threadIdx.x; e < NEDGES;
       e += gridDim.x * blockDim.x) {
    int s = ei[e];
    int d = ei[NEDGES + e];
    atomicAdd(&deg[d], 1);
    atomicAdd(&deg[s], 1);
  }
}

__global__ void scan1_kernel(const int* __restrict__ deg, int* __restrict__ bsum) {
  __shared__ int wsum[16];
  int t = threadIdx.x;
  int i = blockIdx.x * 1024 + t;
  int v = (i < NNODES) ? deg[i] : 0;
  #pragma unroll
  for (int off = 32; off >= 1; off >>= 1) v += __shfl_down(v, off, 64);
  if ((t & 63) == 0) wsum[t >> 6] = v;
  __syncthreads();
  if (t == 0) {
    int s = 0;
    #pragma unroll
    for (int k = 0; k < 16; ++k) s += wsum[k];
    bsum[blockIdx.x] = s;
  }
}

__global__ void scan2_kernel(const int* __restrict__ bsum, int* __restrict__ boff) {
  if (threadIdx.x == 0 && blockIdx.x == 0) {
    int run = 0;
    for (int b = 0; b < SB; ++b) { boff[b] = run; run += bsum[b]; }
  }
}

__global__ void scan3_kernel(const int* __restrict__ deg, const int* __restrict__ boff,
                             int* __restrict__ row_ptr, int* __restrict__ cursor) {
  __shared__ int wsum[16];
  int t = threadIdx.x, lane = t & 63, wv = t >> 6;
  int i = blockIdx.x * 1024 + t;
  int v = (i < NNODES) ? deg[i] : 0;
  int s = v;
  #pragma unroll
  for (int off = 1; off < 64; off <<= 1) {
    int tmp = __shfl_up(s, off, 64);
    if (lane >= off) s += tmp;
  }
  if (lane == 63) wsum[wv] = s;
  __syncthreads();
  if (t == 0) {
    int run = 0;
    #pragma unroll
    for (int k = 0; k < 16; ++k) { int tmp = wsum[k]; wsum[k] = run; run += tmp; }
  }
  __syncthreads();
  int incl = s + wsum[wv] + boff[blockIdx.x];
  if (i < NNODES) {
    row_ptr[i + 1] = incl;
    cursor[i] = incl - v;   // exclusive prefix = fill cursor start
    if (i == 0) row_ptr[0] = 0;
  }
}

__global__ void fill_adj_kernel(const int* __restrict__ ei, int* __restrict__ cursor,
                                int* __restrict__ adj) {
  for (int e = blockIdx.x * blockDim.x + threadIdx.x; e < NEDGES;
       e += gridDim.x * blockDim.x) {
    int s = ei[e];
    int d = ei[NEDGES + e];
    int p = atomicAdd(&cursor[d], 1); adj[p] = s;
    int q = atomicAdd(&cursor[s], 1); adj[q] = d;
  }
}

// ---------------- conversions ----------------

// z_all layout: [MPAD][1024] bf16, row n holds [z0|z1|z2|z3] (256 each).
// Real rows: slot0 = bf16(x); pad rows: all 1024 zeroed (slots 1..3 of real
// rows are written by the spmm hops).
__global__ void convert_x_kernel(const float* __restrict__ x, unsigned short* __restrict__ z) {
  int idx = blockIdx.x * 256 + threadIdx.x;
  int row = idx >> 8;
  int c4 = (idx & 255) << 2;   // 0..1020
  if (row >= MPAD) return;
  if (row < NNODES) {
    if (c4 < FINF) {
      float4 xv = *(const float4*)&x[(size_t)row * FINF + c4];
      ushort4 o;
      o.x = f2bf(xv.x); o.y = f2bf(xv.y); o.z = f2bf(xv.z); o.w = f2bf(xv.w);
      *(ushort4*)&z[(size_t)row * KTOT + c4] = o;
    }
  } else {
    *(ushort4*)&z[(size_t)row * KTOT + c4] = make_ushort4(0, 0, 0, 0);
  }
}

// Bt[o][kk] = weights_flat[kk*256 + o]  (B transposed, bf16), kk = k*256+f.
__global__ void convert_w_kernel(const float* __restrict__ w, unsigned short* __restrict__ Bt) {
  int idx = blockIdx.x * 256 + threadIdx.x;   // 262144 total
  int o = idx >> 10, kk = idx & 1023;
  Bt[idx] = f2bf(w[(size_t)kk * FOUTF + o]);
}

// ---------------- SpMM (gather, one wave per node) ----------------

__global__ __launch_bounds__(256)
void spmm_kernel(const unsigned short* __restrict__ zin,   // z_all + (k-1)*256
                 unsigned short* __restrict__ zout,        // z_all + k*256
                 const int* __restrict__ row_ptr,
                 const int* __restrict__ adj) {
  const int wid = (blockIdx.x * 256 + threadIdx.x) >> 6;
  const int lane = threadIdx.x & 63;
  if (wid >= NNODES) return;
  const int beg = row_ptr[wid];
  const int end = row_ptr[wid + 1];
  const int fo = lane << 2;
  float a0 = 0.f, a1 = 0.f, a2 = 0.f, a3 = 0.f;
  int j = beg;
  for (; j + 4 <= end; j += 4) {
    int n0 = adj[j], n1 = adj[j + 1], n2 = adj[j + 2], n3 = adj[j + 3];
    ushort4 v0 = *(const ushort4*)&zin[(size_t)n0 * KTOT + fo];
    ushort4 v1 = *(const ushort4*)&zin[(size_t)n1 * KTOT + fo];
    ushort4 v2 = *(const ushort4*)&zin[(size_t)n2 * KTOT + fo];
    ushort4 v3 = *(const ushort4*)&zin[(size_t)n3 * KTOT + fo];
    a0 += bf2f(v0.x) + bf2f(v1.x) + bf2f(v2.x) + bf2f(v3.x);
    a1 += bf2f(v0.y) + bf2f(v1.y) + bf2f(v2.y) + bf2f(v3.y);
    a2 += bf2f(v0.z) + bf2f(v1.z) + bf2f(v2.z) + bf2f(v3.z);
    a3 += bf2f(v0.w) + bf2f(v1.w) + bf2f(v2.w) + bf2f(v3.w);
  }
  for (; j < end; ++j) {
    ushort4 v = *(const ushort4*)&zin[(size_t)adj[j] * KTOT + fo];
    a0 += bf2f(v.x); a1 += bf2f(v.y); a2 += bf2f(v.z); a3 += bf2f(v.w);
  }
  ushort4 o;
  o.x = f2bf(a0); o.y = f2bf(a1); o.z = f2bf(a2); o.w = f2bf(a3);
  *(ushort4*)&zout[(size_t)wid * KTOT + fo] = o;
}

// ---------------- GEMM: [MPAD,1024]bf16 @ [1024,256]bf16 -> fp32 ----------------
// m97 structure: 128x128 tile, BK=32, 4 waves (2x2 of 64x64), 16x16x32 MFMA,
// global_load_lds width-16 staging, B pre-transposed so both tiles stage as
// [dim][k] row-major (contiguous 8-k fragments -> ds_read_b128).

__global__ __launch_bounds__(256)
void gemm_kernel(const unsigned short* __restrict__ A,   // [MPAD][1024]
                 const unsigned short* __restrict__ Bt,  // [256][1024]
                 float* __restrict__ C) {                 // [NNODES][256]
  __shared__ __align__(16) unsigned short As[128 * 32];
  __shared__ __align__(16) unsigned short Bs[128 * 32];
  const int tid = threadIdx.x;
  const int lane = tid & 63;
  const int wave = tid >> 6;
  const int bm = blockIdx.x >> 1;
  const int bn = blockIdx.x & 1;
  const int wr = wave >> 1, wc = wave & 1;

  const int rowA_base = bm * 128;
  const int colB_base = bn * 128;
  const int sub_r = lane >> 2;          // 0..15 (row within 16-row chunk)
  const int kp = (lane & 3) << 3;       // 0,8,16,24

  f32x4 acc[4][4] = {};

  for (int k0 = 0; k0 < KTOT; k0 += 32) {
    __syncthreads();
    #pragma unroll
    for (int i = 0; i < 2; ++i) {
      int chunk = i * 4 + wave;         // 0..7, 16 rows of 64B each
      int row = chunk * 16 + sub_r;
      const unsigned short* ga = A + (size_t)(rowA_base + row) * KTOT + k0 + kp;
      async_ld16(ga, &As[chunk * 512]);
      const unsigned short* gb = Bt + (size_t)(colB_base + row) * KTOT + k0 + kp;
      async_ld16(gb, &Bs[chunk * 512]);
    }
    __syncthreads();

    bf16x8 a[4], b[4];
    #pragma unroll
    for (int m = 0; m < 4; ++m)
      a[m] = *(const bf16x8*)&As[(wr * 64 + m * 16 + (lane & 15)) * 32 + (lane >> 4) * 8];
    #pragma unroll
    for (int n = 0; n < 4; ++n)
      b[n] = *(const bf16x8*)&Bs[(wc * 64 + n * 16 + (lane & 15)) * 32 + (lane >> 4) * 8];
    #pragma unroll
    for (int m = 0; m < 4; ++m) {
      #pragma unroll
      for (int n = 0; n < 4; ++n)
        acc[m][n] = __builtin_amdgcn_mfma_f32_16x16x32_bf16(a[m], b[n], acc[m][n], 0, 0, 0);
    }
  }

  // C/D layout: col = lane&15, row = (lane>>4)*4 + j   [m89-verified]
  const int ccol0 = colB_base + wc * 64 + (lane & 15);
  const int crow0 = rowA_base + wr * 64 + ((lane >> 4) << 2);
  #pragma unroll
  for (int m = 0; m < 4; ++m) {
    #pragma unroll
    for (int j = 0; j < 4; ++j) {
      int r = crow0 + m * 16 + j;
      if (r < NNODES) {
        float* cp = C + (size_t)r * FOUTF + ccol0;
        #pragma unroll
        for (int n = 0; n < 4; ++n) cp[n * 16] = acc[m][n][j];
      }
    }
  }
}

// ---------------- launch ----------------

extern "C" void kernel_launch(void* const* d_in, const int* in_sizes, int n_in,
                              void* d_out, int out_size, void* d_ws, size_t ws_size,
                              hipStream_t stream) {
  (void)in_sizes; (void)n_in; (void)out_size;
  const float* x  = (const float*)d_in[0];
  const int*   ei = (const int*)d_in[1];
  const float* w  = (const float*)d_in[2];
  float* out = (float*)d_out;

  // workspace carve (needs ~232 MB)
  char* ws = (char*)d_ws;
  size_t off = 0;
  auto carve = [&](size_t bytes) -> void* {
    void* p = ws + off;
    off = (off + bytes + 255) & ~(size_t)255;
    return p;
  };
  unsigned short* z       = (unsigned short*)carve((size_t)MPAD * KTOT * 2);
  unsigned short* Bt      = (unsigned short*)carve((size_t)FOUTF * KTOT * 2);
  int* row_ptr            = (int*)carve((size_t)(NNODES + 1) * 4);
  int* cursor             = (int*)carve((size_t)NNODES * 4);
  int* deg                = (int*)carve((size_t)NNODES * 4);
  int* bsum               = (int*)carve((size_t)SB * 4);
  int* boff               = (int*)carve((size_t)SB * 4);
  int* adj                = (int*)carve((size_t)2 * NEDGES * 4);
  (void)ws_size;

  hipMemsetAsync(deg, 0, (size_t)NNODES * 4, stream);

  count_deg_kernel<<<2048, 256, 0, stream>>>(ei, deg);
  scan1_kernel<<<SB, 1024, 0, stream>>>(deg, bsum);
  scan2_kernel<<<1, 64, 0, stream>>>(bsum, boff);
  scan3_kernel<<<SB, 1024, 0, stream>>>(deg, boff, row_ptr, cursor);
  fill_adj_kernel<<<2048, 256, 0, stream>>>(ei, cursor, adj);

  convert_x_kernel<<<MPAD, 256, 0, stream>>>(x, z);
  convert_w_kernel<<<1024, 256, 0, stream>>>(w, Bt);

  // 3 hops: slot k-1 -> slot k
  for (int k = 1; k < 4; ++k) {
    spmm_kernel<<<(NNODES + 3) / 4, 256, 0, stream>>>(
        z + (size_t)(k - 1) * FINF, z + (size_t)k * FINF, row_ptr, adj);
  }

  gemm_kernel<<<MTILES * 2, 256, 0, stream>>>(z, Bt, out);
}

// Round 2
// 1561.469 us; speedup vs baseline: 1.3957x; 1.3957x over previous
//
#include <hip/hip_runtime.h>
#include <hip/hip_bf16.h>

// GraphFilter: out = sum_k (S^k x) @ W_k,  S = symmetric scatter-add adjacency
// N=100000, E=3200000, FIN=FOUT=256, K=4.
// Round 2: replace atomic-scatter CSR build (fill_adj 570us, 15x write
// amplification) with bucketed radix partition -> per-bucket CSR finalize.
// SpMM (gather, wave/node) and fused MFMA GEMM unchanged.

#define NNODES 100000
#define NEDGES 3200000
#define FINF   256
#define FOUTF  256
#define KTOT   1024            // K * FIN
#define MPAD   100096          // 782 * 128 (M padded to 128-row tiles)
#define MTILES 782
#define NB     782             // node buckets: node >> 7, 128 nodes each
#define FILLB  1024            // bin_fill blocks
#define CHUNK  3125            // edges per bin_fill block (1024*3125 = 3.2M)

typedef __attribute__((ext_vector_type(8))) short bf16x8;
typedef __attribute__((ext_vector_type(4))) float f32x4;

__device__ __forceinline__ float bf2f(unsigned short u) {
  return __uint_as_float(((unsigned int)u) << 16);
}
__device__ __forceinline__ unsigned short f2bf(float f) {
  unsigned int u = __float_as_uint(f);
  unsigned int r = (u + 0x7fffu + ((u >> 16) & 1u)) >> 16;
  return (unsigned short)r;
}

__device__ __forceinline__ void async_ld16(const void* g, void* l) {
  __builtin_amdgcn_global_load_lds(
      (const __attribute__((address_space(1))) unsigned int*)g,
      (__attribute__((address_space(3))) unsigned int*)l, 16, 0, 0);
}

// ---------------- bucketed CSR build ----------------

// 1) per-block LDS histogram of (owner) buckets, one global merge per block.
__global__ __launch_bounds__(256)
void bucket_count_kernel(const int* __restrict__ ei, int* __restrict__ bcount) {
  __shared__ int h[NB];
  for (int i = threadIdx.x; i < NB; i += 256) h[i] = 0;
  __syncthreads();
  for (int e = blockIdx.x * 256 + threadIdx.x; e < NEDGES; e += gridDim.x * 256) {
    int s = ei[e];
    int d = ei[NEDGES + e];
    atomicAdd(&h[d >> 7], 1);
    atomicAdd(&h[s >> 7], 1);
  }
  __syncthreads();
  for (int i = threadIdx.x; i < NB; i += 256) {
    int c = h[i];
    if (c) atomicAdd(&bcount[i], c);
  }
}

// 2) exclusive scan of 782 bucket counts (single block, 1024 threads).
__global__ __launch_bounds__(1024)
void bucket_scan_kernel(const int* __restrict__ bcount, int* __restrict__ bbase,
                        int* __restrict__ bcursor) {
  __shared__ int ws[16];
  int t = threadIdx.x, lane = t & 63, wv = t >> 6;
  int v = (t < NB) ? bcount[t] : 0;
  int s = v;
  #pragma unroll
  for (int off = 1; off < 64; off <<= 1) {
    int tmp = __shfl_up(s, off, 64);
    if (lane >= off) s += tmp;
  }
  if (lane == 63) ws[wv] = s;
  __syncthreads();
  if (t == 0) {
    int run = 0;
    #pragma unroll
    for (int k = 0; k < 16; ++k) { int tmp = ws[k]; ws[k] = run; run += tmp; }
  }
  __syncthreads();
  int excl = s + ws[wv] - v;
  if (t < NB) { bbase[t] = excl; bcursor[t] = excl; }
  if (t == NB) bbase[NB] = excl;   // total = 2E
}

// 3) chunked partition: block claims per-bucket ranges once, then streams
// packed (owner<<32 | nbr) entries; ~782 active lines -> L2-resident writes.
__global__ __launch_bounds__(256)
void bin_fill_kernel(const int* __restrict__ ei, int* __restrict__ bcursor,
                     unsigned long long* __restrict__ binned) {
  __shared__ int h[NB];
  for (int i = threadIdx.x; i < NB; i += 256) h[i] = 0;
  __syncthreads();
  const int e0 = blockIdx.x * CHUNK;
  const int e1 = (e0 + CHUNK < NEDGES) ? e0 + CHUNK : NEDGES;
  for (int e = e0 + threadIdx.x; e < e1; e += 256) {
    int s = ei[e];
    int d = ei[NEDGES + e];
    atomicAdd(&h[d >> 7], 1);
    atomicAdd(&h[s >> 7], 1);
  }
  __syncthreads();
  for (int i = threadIdx.x; i < NB; i += 256) {
    int c = h[i];
    h[i] = c ? atomicAdd(&bcursor[i], c) : 0;
  }
  __syncthreads();
  for (int e = e0 + threadIdx.x; e < e1; e += 256) {
    int s = ei[e];
    int d = ei[NEDGES + e];
    int p = atomicAdd(&h[d >> 7], 1);
    binned[p] = ((unsigned long long)d << 32) | (unsigned int)s;
    int q = atomicAdd(&h[s >> 7], 1);
    binned[q] = ((unsigned long long)s << 32) | (unsigned int)d;
  }
}

// 4) per-bucket CSR finalize: 128-node local degree count + scan in LDS,
// write row_ptr, scatter nbr into the bucket's contiguous adj window.
__global__ __launch_bounds__(256)
void bucket_csr_kernel(const unsigned long long* __restrict__ binned,
                       const int* __restrict__ bbase,
                       int* __restrict__ row_ptr, int* __restrict__ adj) {
  __shared__ int cnt[128];
  __shared__ int cur[128];
  const int b = blockIdx.x;
  const int node0 = b << 7;
  const int base = bbase[b];
  const int end = bbase[b + 1];
  const int tid = threadIdx.x;
  if (tid < 128) cnt[tid] = 0;
  __syncthreads();
  for (int i = base + tid; i < end; i += 256) {
    unsigned long long v = binned[i];
    int owner = (int)(v >> 32);
    atomicAdd(&cnt[owner - node0], 1);
  }
  __syncthreads();
  if (tid < 128) {
    int ex = 0;
    #pragma unroll 8
    for (int j = 0; j < 128; ++j) {   // broadcast LDS reads, uniform loop
      int c = cnt[j];
      ex += (j < tid) ? c : 0;
    }
    int node = node0 + tid;
    if (node < NNODES) row_ptr[node] = base + ex;
    cur[tid] = base + ex;
  }
  if (tid == 0 && b == NB - 1) row_ptr[NNODES] = end;
  __syncthreads();
  for (int i = base + tid; i < end; i += 256) {
    unsigned long long v = binned[i];
    int owner = (int)(v >> 32);
    int nbr = (int)(v & 0xffffffffu);
    int p = atomicAdd(&cur[owner - node0], 1);
    adj[p] = nbr;
  }
}

// ---------------- conversions ----------------

// z_all layout: [MPAD][1024] bf16, row n holds [z0|z1|z2|z3] (256 each).
__global__ void convert_x_kernel(const float* __restrict__ x, unsigned short* __restrict__ z) {
  int idx = blockIdx.x * 256 + threadIdx.x;
  int row = idx >> 8;
  int c4 = (idx & 255) << 2;   // 0..1020
  if (row >= MPAD) return;
  if (row < NNODES) {
    if (c4 < FINF) {
      float4 xv = *(const float4*)&x[(size_t)row * FINF + c4];
      ushort4 o;
      o.x = f2bf(xv.x); o.y = f2bf(xv.y); o.z = f2bf(xv.z); o.w = f2bf(xv.w);
      *(ushort4*)&z[(size_t)row * KTOT + c4] = o;
    }
  } else {
    *(ushort4*)&z[(size_t)row * KTOT + c4] = make_ushort4(0, 0, 0, 0);
  }
}

// Bt[o][kk] = weights_flat[kk*256 + o]  (B transposed, bf16), kk = k*256+f.
__global__ void convert_w_kernel(const float* __restrict__ w, unsigned short* __restrict__ Bt) {
  int idx = blockIdx.x * 256 + threadIdx.x;   // 262144 total
  int o = idx >> 10, kk = idx & 1023;
  Bt[idx] = f2bf(w[(size_t)kk * FOUTF + o]);
}

// ---------------- SpMM (gather, one wave per node) ----------------

__global__ __launch_bounds__(256)
void spmm_kernel(const unsigned short* __restrict__ zin,   // z_all + (k-1)*256
                 unsigned short* __restrict__ zout,        // z_all + k*256
                 const int* __restrict__ row_ptr,
                 const int* __restrict__ adj) {
  const int wid = (blockIdx.x * 256 + threadIdx.x) >> 6;
  const int lane = threadIdx.x & 63;
  if (wid >= NNODES) return;
  const int beg = row_ptr[wid];
  const int end = row_ptr[wid + 1];
  const int fo = lane << 2;
  float a0 = 0.f, a1 = 0.f, a2 = 0.f, a3 = 0.f;
  int j = beg;
  for (; j + 4 <= end; j += 4) {
    int n0 = adj[j], n1 = adj[j + 1], n2 = adj[j + 2], n3 = adj[j + 3];
    ushort4 v0 = *(const ushort4*)&zin[(size_t)n0 * KTOT + fo];
    ushort4 v1 = *(const ushort4*)&zin[(size_t)n1 * KTOT + fo];
    ushort4 v2 = *(const ushort4*)&zin[(size_t)n2 * KTOT + fo];
    ushort4 v3 = *(const ushort4*)&zin[(size_t)n3 * KTOT + fo];
    a0 += bf2f(v0.x) + bf2f(v1.x) + bf2f(v2.x) + bf2f(v3.x);
    a1 += bf2f(v0.y) + bf2f(v1.y) + bf2f(v2.y) + bf2f(v3.y);
    a2 += bf2f(v0.z) + bf2f(v1.z) + bf2f(v2.z) + bf2f(v3.z);
    a3 += bf2f(v0.w) + bf2f(v1.w) + bf2f(v2.w) + bf2f(v3.w);
  }
  for (; j < end; ++j) {
    ushort4 v = *(const ushort4*)&zin[(size_t)adj[j] * KTOT + fo];
    a0 += bf2f(v.x); a1 += bf2f(v.y); a2 += bf2f(v.z); a3 += bf2f(v.w);
  }
  ushort4 o;
  o.x = f2bf(a0); o.y = f2bf(a1); o.z = f2bf(a2); o.w = f2bf(a3);
  *(ushort4*)&zout[(size_t)wid * KTOT + fo] = o;
}

// ---------------- GEMM: [MPAD,1024]bf16 @ [1024,256]bf16 -> fp32 ----------------

__global__ __launch_bounds__(256)
void gemm_kernel(const unsigned short* __restrict__ A,   // [MPAD][1024]
                 const unsigned short* __restrict__ Bt,  // [256][1024]
                 float* __restrict__ C) {                 // [NNODES][256]
  __shared__ __align__(16) unsigned short As[128 * 32];
  __shared__ __align__(16) unsigned short Bs[128 * 32];
  const int tid = threadIdx.x;
  const int lane = tid & 63;
  const int wave = tid >> 6;
  const int bm = blockIdx.x >> 1;
  const int bn = blockIdx.x & 1;
  const int wr = wave >> 1, wc = wave & 1;

  const int rowA_base = bm * 128;
  const int colB_base = bn * 128;
  const int sub_r = lane >> 2;          // 0..15
  const int kp = (lane & 3) << 3;       // 0,8,16,24

  f32x4 acc[4][4] = {};

  for (int k0 = 0; k0 < KTOT; k0 += 32) {
    __syncthreads();
    #pragma unroll
    for (int i = 0; i < 2; ++i) {
      int chunk = i * 4 + wave;         // 0..7, 16 rows of 64B each
      int row = chunk * 16 + sub_r;
      const unsigned short* ga = A + (size_t)(rowA_base + row) * KTOT + k0 + kp;
      async_ld16(ga, &As[chunk * 512]);
      const unsigned short* gb = Bt + (size_t)(colB_base + row) * KTOT + k0 + kp;
      async_ld16(gb, &Bs[chunk * 512]);
    }
    __syncthreads();

    bf16x8 a[4], b[4];
    #pragma unroll
    for (int m = 0; m < 4; ++m)
      a[m] = *(const bf16x8*)&As[(wr * 64 + m * 16 + (lane & 15)) * 32 + (lane >> 4) * 8];
    #pragma unroll
    for (int n = 0; n < 4; ++n)
      b[n] = *(const bf16x8*)&Bs[(wc * 64 + n * 16 + (lane & 15)) * 32 + (lane >> 4) * 8];
    #pragma unroll
    for (int m = 0; m < 4; ++m) {
      #pragma unroll
      for (int n = 0; n < 4; ++n)
        acc[m][n] = __builtin_amdgcn_mfma_f32_16x16x32_bf16(a[m], b[n], acc[m][n], 0, 0, 0);
    }
  }

  // C/D layout: col = lane&15, row = (lane>>4)*4 + j   [m89-verified]
  const int ccol0 = colB_base + wc * 64 + (lane & 15);
  const int crow0 = rowA_base + wr * 64 + ((lane >> 4) << 2);
  #pragma unroll
  for (int m = 0; m < 4; ++m) {
    #pragma unroll
    for (int j = 0; j < 4; ++j) {
      int r = crow0 + m * 16 + j;
      if (r < NNODES) {
        float* cp = C + (size_t)r * FOUTF + ccol0;
        #pragma unroll
        for (int n = 0; n < 4; ++n) cp[n * 16] = acc[m][n][j];
      }
    }
  }
}

// ---------------- launch ----------------

extern "C" void kernel_launch(void* const* d_in, const int* in_sizes, int n_in,
                              void* d_out, int out_size, void* d_ws, size_t ws_size,
                              hipStream_t stream) {
  (void)in_sizes; (void)n_in; (void)out_size; (void)ws_size;
  const float* x  = (const float*)d_in[0];
  const int*   ei = (const int*)d_in[1];
  const float* w  = (const float*)d_in[2];
  float* out = (float*)d_out;

  char* ws = (char*)d_ws;
  size_t off = 0;
  auto carve = [&](size_t bytes) -> void* {
    void* p = ws + off;
    off = (off + bytes + 255) & ~(size_t)255;
    return p;
  };
  unsigned short* z  = (unsigned short*)carve((size_t)MPAD * KTOT * 2);  // 205 MB
  unsigned short* Bt = (unsigned short*)carve((size_t)FOUTF * KTOT * 2);
  int* row_ptr       = (int*)carve((size_t)(NNODES + 1) * 4);
  int* adj           = (int*)carve((size_t)2 * NEDGES * 4);              // 25.6 MB
  int* bcount        = (int*)carve((size_t)(NB + 1) * 4);
  int* bbase         = (int*)carve((size_t)(NB + 1) * 4);
  int* bcursor       = (int*)carve((size_t)(NB + 1) * 4);
  // binned (51.2 MB) aliases the head of z: dead before convert_x runs
  // (stream-ordered), and convert_x/spmm rewrite every byte of z they read.
  unsigned long long* binned = (unsigned long long*)z;

  hipMemsetAsync(bcount, 0, (size_t)(NB + 1) * 4, stream);

  bucket_count_kernel<<<1024, 256, 0, stream>>>(ei, bcount);
  bucket_scan_kernel<<<1, 1024, 0, stream>>>(bcount, bbase, bcursor);
  bin_fill_kernel<<<FILLB, 256, 0, stream>>>(ei, bcursor, binned);
  bucket_csr_kernel<<<NB, 256, 0, stream>>>(binned, bbase, row_ptr, adj);

  convert_x_kernel<<<MPAD, 256, 0, stream>>>(x, z);
  convert_w_kernel<<<1024, 256, 0, stream>>>(w, Bt);

  for (int k = 1; k < 4; ++k) {
    spmm_kernel<<<(NNODES + 3) / 4, 256, 0, stream>>>(
        z + (size_t)(k - 1) * FINF, z + (size_t)k * FINF, row_ptr, adj);
  }

  gemm_kernel<<<MTILES * 2, 256, 0, stream>>>(z, Bt, out);
}